// Round 1
// baseline (474.668 us; speedup 1.0000x reference)
//
#include <hip/hip_runtime.h>
#include <cstdint>

// ---------------------------------------------------------------------------
// VAE attention block: GN -> QKV 1x1 conv -> softmax(QK^T/sqrt(C)) V -> proj + x
// B=4, H=W=64 (N=4096 pixels/batch), C=512, GROUPS=32 (16 ch/group)
// Strategy: fp32 GN stats, bf16 MFMA GEMMs (m97 structure: 128x128 tile, BK=64,
// global_load_lds width=16, B^T operand layout), in-place bf16 softmax.
// ---------------------------------------------------------------------------

typedef __bf16 bf16_t;
typedef bf16_t bf16x8 __attribute__((ext_vector_type(8)));
typedef float floatx4 __attribute__((ext_vector_type(4)));

__device__ __forceinline__ uint16_t f2b(float f) {
    // round-to-nearest-even bf16
    uint32_t u = __builtin_bit_cast(uint32_t, f);
    u += 0x7fffu + ((u >> 16) & 1u);
    return (uint16_t)(u >> 16);
}
__device__ __forceinline__ float b2f(uint16_t h) {
    uint32_t u = ((uint32_t)h) << 16;
    return __builtin_bit_cast(float, u);
}

__device__ __forceinline__ void lds_copy16(void* lds, const void* glob) {
    __builtin_amdgcn_global_load_lds(
        (__attribute__((address_space(1))) void*)(void*)glob,
        (__attribute__((address_space(3))) void*)lds,
        16, 0, 0);
}

// ---------------------------------------------------------------------------
// GroupNorm stats: one block per (batch, group). 64*64*16 = 65536 elems each.
// ---------------------------------------------------------------------------
__global__ __launch_bounds__(256) void gn_stats(const float* __restrict__ x,
                                                float* __restrict__ stats) {
    const int bg = blockIdx.x;            // 0..127
    const int b = bg >> 5, g = bg & 31;
    const float* base = x + (long)b * (4096L * 512) + g * 16;
    const int tid = threadIdx.x;
    float s = 0.f, sq = 0.f;
    #pragma unroll 8
    for (int i = 0; i < 64; i++) {
        int idx4 = tid + i * 256;          // float4 index within group
        int pixel = idx4 >> 2, c4 = idx4 & 3;
        const float4 v = *(const float4*)(base + (long)pixel * 512 + c4 * 4);
        s += v.x + v.y + v.z + v.w;
        sq += v.x * v.x + v.y * v.y + v.z * v.z + v.w * v.w;
    }
    #pragma unroll
    for (int off = 32; off > 0; off >>= 1) {
        s += __shfl_down(s, off);
        sq += __shfl_down(sq, off);
    }
    __shared__ float rs[4], rq[4];
    const int lane = tid & 63, w = tid >> 6;
    if (lane == 0) { rs[w] = s; rq[w] = sq; }
    __syncthreads();
    if (tid == 0) {
        float S = rs[0] + rs[1] + rs[2] + rs[3];
        float Q = rq[0] + rq[1] + rq[2] + rq[3];
        float mean = S * (1.f / 65536.f);
        float var = Q * (1.f / 65536.f) - mean * mean;
        stats[bg * 2 + 0] = mean;
        stats[bg * 2 + 1] = rsqrtf(var + 1e-5f);
    }
}

// ---------------------------------------------------------------------------
// GroupNorm apply: h_bf16 = (x-mean)*rstd*gamma + beta.  4 elems/thread.
// ---------------------------------------------------------------------------
__global__ __launch_bounds__(256) void gn_apply(const float* __restrict__ x,
                                                const float* __restrict__ stats,
                                                const float* __restrict__ gamma,
                                                const float* __restrict__ beta,
                                                uint16_t* __restrict__ h) {
    const long idx4 = (long)blockIdx.x * 256 + threadIdx.x;   // 0..2097151
    const long e0 = idx4 * 4;
    const int c = (int)(e0 & 511);
    const int b = (int)(e0 >> 21);                            // 4096*512 = 2^21
    const float2 st = ((const float2*)stats)[b * 32 + (c >> 4)];
    const float4 v = ((const float4*)x)[idx4];
    const float4 gm = ((const float4*)gamma)[c >> 2];
    const float4 bt = ((const float4*)beta)[c >> 2];
    union { ushort4 u; uint16_t s[4]; } o;
    o.s[0] = f2b((v.x - st.x) * st.y * gm.x + bt.x);
    o.s[1] = f2b((v.y - st.x) * st.y * gm.y + bt.y);
    o.s[2] = f2b((v.z - st.x) * st.y * gm.z + bt.z);
    o.s[3] = f2b((v.w - st.x) * st.y * gm.w + bt.w);
    ((ushort4*)h)[idx4] = o.u;
}

// ---------------------------------------------------------------------------
// Cast+transpose weights: wT[d][c] = bf16(w[c][d]), 512x512, 64x64 LDS tiles.
// grid (8, 8, 4): z selects which weight matrix.
// ---------------------------------------------------------------------------
__global__ __launch_bounds__(256) void wcast_transpose(const float* __restrict__ w0,
                                                       const float* __restrict__ w1,
                                                       const float* __restrict__ w2,
                                                       const float* __restrict__ w3,
                                                       uint16_t* __restrict__ out) {
    const float* ws[4] = {w0, w1, w2, w3};
    const float* w = ws[blockIdx.z];
    uint16_t* o = out + (long)blockIdx.z * 512 * 512;
    __shared__ uint16_t t[64][65];
    const int nb = blockIdx.x * 64, kb = blockIdx.y * 64;
    const int lc = threadIdx.x & 63, lg = threadIdx.x >> 6;
    #pragma unroll
    for (int i = 0; i < 16; i++) {
        int r = lg * 16 + i;
        t[lc][r] = f2b(w[(long)(kb + r) * 512 + nb + lc]);   // t[n_loc][k_loc]
    }
    __syncthreads();
    #pragma unroll
    for (int i = 0; i < 16; i++) {
        int r = lg * 16 + i;
        o[(long)(nb + r) * 512 + kb + lc] = t[r][lc];        // wT[n][k]
    }
}

// ---------------------------------------------------------------------------
// Transpose v (bf16): vT[b][c][n] = v[b][n][c].  64x64 tiles, grid (8, 64, 4).
// ---------------------------------------------------------------------------
__global__ __launch_bounds__(256) void transpose_v(const uint16_t* __restrict__ v,
                                                   uint16_t* __restrict__ vt) {
    __shared__ uint16_t t[64][65];
    const long zb = blockIdx.z;
    const uint16_t* in = v + zb * (4096L * 512);
    uint16_t* out = vt + zb * (512L * 4096);
    const int cb = blockIdx.x * 64;    // channel tile
    const int rb = blockIdx.y * 64;    // pixel tile
    const int lc = threadIdx.x & 63, lg = threadIdx.x >> 6;
    #pragma unroll
    for (int i = 0; i < 16; i++) {
        int r = lg * 16 + i;
        t[lc][r] = in[(long)(rb + r) * 512 + cb + lc];
    }
    __syncthreads();
    #pragma unroll
    for (int i = 0; i < 16; i++) {
        int r = lg * 16 + i;
        out[(long)(cb + r) * 4096 + rb + lc] = t[r][lc];
    }
}

// ---------------------------------------------------------------------------
// In-place row softmax on bf16 scores. One block per row (4096 cols).
// ---------------------------------------------------------------------------
__global__ __launch_bounds__(256) void softmax_inplace(uint16_t* __restrict__ s) {
    const long row = blockIdx.x;
    uint16_t* p = s + row * 4096;
    const int tid = threadIdx.x;
    union { uint4 u; uint16_t s16[8]; } d0, d1;
    d0.u = ((const uint4*)p)[tid * 2 + 0];
    d1.u = ((const uint4*)p)[tid * 2 + 1];
    float x[16];
    #pragma unroll
    for (int j = 0; j < 8; j++) { x[j] = b2f(d0.s16[j]); x[8 + j] = b2f(d1.s16[j]); }

    float m = -3.0e38f;
    #pragma unroll
    for (int j = 0; j < 16; j++) m = fmaxf(m, x[j]);
    #pragma unroll
    for (int off = 32; off > 0; off >>= 1) m = fmaxf(m, __shfl_xor(m, off));
    __shared__ float rm[4];
    const int lane = tid & 63, w = tid >> 6;
    if (lane == 0) rm[w] = m;
    __syncthreads();
    m = fmaxf(fmaxf(rm[0], rm[1]), fmaxf(rm[2], rm[3]));

    float sum = 0.f;
    #pragma unroll
    for (int j = 0; j < 16; j++) { x[j] = __expf(x[j] - m); sum += x[j]; }
    #pragma unroll
    for (int off = 32; off > 0; off >>= 1) sum += __shfl_xor(sum, off);
    __shared__ float rsum[4];
    if (lane == 0) rsum[w] = sum;
    __syncthreads();
    sum = rsum[0] + rsum[1] + rsum[2] + rsum[3];
    const float inv = 1.f / sum;

    #pragma unroll
    for (int j = 0; j < 8; j++) { d0.s16[j] = f2b(x[j] * inv); d1.s16[j] = f2b(x[8 + j] * inv); }
    ((uint4*)p)[tid * 2 + 0] = d0.u;
    ((uint4*)p)[tid * 2 + 1] = d1.u;
}

// ---------------------------------------------------------------------------
// Templated bf16 MFMA GEMM, m97 structure.
// C[m,n] = sum_k A[m,k] * Bt[n,k]   (both row-major with K contiguous)
// MODE 0: bf16 out, (acc + bias[n]) * scale
// MODE 1: bf16 out, plain
// MODE 2: f32 out, acc + bias[n] + resid[m*N+n]
// Tile: 128x128, BK=64, 4 waves each computing 64x64 via 4x4 of 16x16x32 MFMA.
// ---------------------------------------------------------------------------
template <int MODE>
__global__ __launch_bounds__(256) void gemm_bt(const uint16_t* __restrict__ A,
                                               const uint16_t* __restrict__ B,
                                               void* __restrict__ Cout,
                                               const float* __restrict__ bias,
                                               const float* __restrict__ resid,
                                               float scale, int M, int N, int K,
                                               long aStride, long bStride, long cStride) {
    __shared__ __align__(16) uint16_t sA[128 * 64];
    __shared__ __align__(16) uint16_t sB[128 * 64];

    const int tid = threadIdx.x;
    const int bz = blockIdx.z;
    const long m0 = (long)blockIdx.y * 128;
    const long n0 = (long)blockIdx.x * 128;
    const uint16_t* Ab = A + (long)bz * aStride;
    const uint16_t* Bb = B + (long)bz * bStride;

    const int lane = tid & 63;
    const int wave = tid >> 6;
    const int wm = (wave & 1) * 64;
    const int wn = (wave >> 1) * 64;
    const int fr = lane & 15;          // fragment row (m for A, n for B)
    const int fk = (lane >> 4) * 8;    // k offset within 32-chunk

    floatx4 acc[4][4];
    #pragma unroll
    for (int i = 0; i < 4; i++)
        #pragma unroll
        for (int j = 0; j < 4; j++) acc[i][j] = (floatx4){0.f, 0.f, 0.f, 0.f};

    for (int kt = 0; kt < K; kt += 64) {
        __syncthreads();   // previous compute done before overwriting LDS
        #pragma unroll
        for (int i = 0; i < 4; i++) {
            const int c = i * 256 + tid;        // chunk id: lane-linear per wave
            const int row = c >> 3;
            const int kk = (c & 7) * 8;
            lds_copy16(&sA[c * 8], Ab + (m0 + row) * (long)K + kt + kk);
            lds_copy16(&sB[c * 8], Bb + (n0 + row) * (long)K + kt + kk);
        }
        __syncthreads();   // drains vmcnt before barrier (compiler-enforced)
        #pragma unroll
        for (int kk = 0; kk < 64; kk += 32) {
            bf16x8 av[4], bv[4];
            #pragma unroll
            for (int mi = 0; mi < 4; mi++)
                av[mi] = *(const bf16x8*)&sA[(wm + mi * 16 + fr) * 64 + kk + fk];
            #pragma unroll
            for (int ni = 0; ni < 4; ni++)
                bv[ni] = *(const bf16x8*)&sB[(wn + ni * 16 + fr) * 64 + kk + fk];
            #pragma unroll
            for (int mi = 0; mi < 4; mi++)
                #pragma unroll
                for (int ni = 0; ni < 4; ni++)
                    acc[mi][ni] = __builtin_amdgcn_mfma_f32_16x16x32_bf16(
                        av[mi], bv[ni], acc[mi][ni], 0, 0, 0);
        }
    }

    // Epilogue.  C/D layout (verified m89/m91): col = lane&15, row = quad*4+reg
    const int quad = lane >> 4;
    #pragma unroll
    for (int ni = 0; ni < 4; ni++) {
        const long col = n0 + wn + ni * 16 + fr;
        const float bv_ = (MODE == 1) ? 0.f : bias[col];
        #pragma unroll
        for (int mi = 0; mi < 4; mi++) {
            #pragma unroll
            for (int r = 0; r < 4; r++) {
                const long row = m0 + wm + mi * 16 + quad * 4 + r;
                float v = acc[mi][ni][r];
                if (MODE == 0) {
                    v = (v + bv_) * scale;
                    ((uint16_t*)Cout)[(long)bz * cStride + row * (long)N + col] = f2b(v);
                } else if (MODE == 1) {
                    ((uint16_t*)Cout)[(long)bz * cStride + row * (long)N + col] = f2b(v);
                } else {
                    v = v + bv_ + resid[row * (long)N + col];
                    ((float*)Cout)[row * (long)N + col] = v;
                }
            }
        }
    }
}

// ---------------------------------------------------------------------------
extern "C" void kernel_launch(void* const* d_in, const int* in_sizes, int n_in,
                              void* d_out, int out_size, void* d_ws, size_t ws_size,
                              hipStream_t stream) {
    const float* x  = (const float*)d_in[0];
    const float* gg = (const float*)d_in[1];
    const float* gb = (const float*)d_in[2];
    const float* wq = (const float*)d_in[3];
    const float* bq = (const float*)d_in[4];
    const float* wk = (const float*)d_in[5];
    const float* bk = (const float*)d_in[6];
    const float* wv = (const float*)d_in[7];
    const float* bv = (const float*)d_in[8];
    const float* wp = (const float*)d_in[9];
    const float* bp = (const float*)d_in[10];
    float* out = (float*)d_out;

    char* ws = (char*)d_ws;
    size_t off = 0;
    auto alloc = [&](size_t bytes) {
        char* p = ws + off;
        off += (bytes + 255) & ~(size_t)255;
        return p;
    };
    float*    stats = (float*)alloc(128 * 2 * sizeof(float));
    uint16_t* h     = (uint16_t*)alloc(16384L * 512 * 2);
    uint16_t* wT    = (uint16_t*)alloc(4L * 512 * 512 * 2);
    uint16_t* q     = (uint16_t*)alloc(16384L * 512 * 2);
    uint16_t* k     = (uint16_t*)alloc(16384L * 512 * 2);
    uint16_t* v     = (uint16_t*)alloc(16384L * 512 * 2);
    uint16_t* vt    = (uint16_t*)alloc(16384L * 512 * 2);
    uint16_t* sc    = (uint16_t*)alloc(4L * 4096 * 4096 * 2);
    uint16_t* ao    = (uint16_t*)alloc(16384L * 512 * 2);
    if (off > ws_size) return;  // workspace too small -> fail visibly

    gn_stats<<<128, 256, 0, stream>>>(x, stats);
    gn_apply<<<8192, 256, 0, stream>>>(x, stats, gg, gb, h);
    wcast_transpose<<<dim3(8, 8, 4), 256, 0, stream>>>(wq, wk, wv, wp, wT);

    const float qscale = 0.04419417382415922f;  // 512^-0.5
    // QKV projections: [16384,512] x [512,512]
    gemm_bt<0><<<dim3(4, 128, 1), 256, 0, stream>>>(h, wT,              q, bq, nullptr, qscale,
                                                    16384, 512, 512, 0, 0, 0);
    gemm_bt<0><<<dim3(4, 128, 1), 256, 0, stream>>>(h, wT + 262144,     k, bk, nullptr, 1.f,
                                                    16384, 512, 512, 0, 0, 0);
    gemm_bt<0><<<dim3(4, 128, 1), 256, 0, stream>>>(h, wT + 2 * 262144, v, bv, nullptr, 1.f,
                                                    16384, 512, 512, 0, 0, 0);
    // scores[b] = q[b] @ k[b]^T  (scale already folded into q)
    gemm_bt<1><<<dim3(32, 32, 4), 256, 0, stream>>>(q, k, sc, nullptr, nullptr, 1.f,
                                                    4096, 4096, 512,
                                                    4096L * 512, 4096L * 512, 4096L * 4096);
    softmax_inplace<<<16384, 256, 0, stream>>>(sc);
    transpose_v<<<dim3(8, 64, 4), 256, 0, stream>>>(v, vt);
    // attn_out[b] = attn[b] @ v[b]
    gemm_bt<1><<<dim3(4, 32, 4), 256, 0, stream>>>(sc, vt, ao, nullptr, nullptr, 1.f,
                                                   4096, 512, 4096,
                                                   4096L * 4096, 512L * 4096, 4096L * 512);
    // out = x + attn_out @ wp + bp
    gemm_bt<2><<<dim3(4, 128, 1), 256, 0, stream>>>(ao, wT + 3 * 262144, out, bp, x, 1.f,
                                                    16384, 512, 512, 0, 0, 0);
}

// Round 2
// 435.204 us; speedup vs baseline: 1.0907x; 1.0907x over previous
//
#include <hip/hip_runtime.h>
#include <cstdint>

// ---------------------------------------------------------------------------
// VAE attention block: GN -> QKV 1x1 conv -> softmax(QK^T/sqrt(C)) V -> proj + x
// B=4, H=W=64 (N=4096 pixels/batch), C=512, GROUPS=32 (16 ch/group)
// R2: gemm_bt gains (1) XOR-swizzled LDS staging (kills 16-way bank conflicts
// on fragment ds_read_b128; swizzle applied to the GLOBAL source address since
// global_load_lds LDS dests must stay lane-linear), (2) coalesced bf16
// epilogue via LDS repack (was 64 scattered 2B stores/lane).
// ---------------------------------------------------------------------------

typedef __bf16 bf16_t;
typedef bf16_t bf16x8 __attribute__((ext_vector_type(8)));
typedef float floatx4 __attribute__((ext_vector_type(4)));

__device__ __forceinline__ uint16_t f2b(float f) {
    uint32_t u = __builtin_bit_cast(uint32_t, f);
    u += 0x7fffu + ((u >> 16) & 1u);
    return (uint16_t)(u >> 16);
}
__device__ __forceinline__ float b2f(uint16_t h) {
    uint32_t u = ((uint32_t)h) << 16;
    return __builtin_bit_cast(float, u);
}

__device__ __forceinline__ void lds_copy16(void* lds, const void* glob) {
    __builtin_amdgcn_global_load_lds(
        (__attribute__((address_space(1))) void*)(void*)glob,
        (__attribute__((address_space(3))) void*)lds,
        16, 0, 0);
}

// ---------------------------------------------------------------------------
// GroupNorm stats: one block per (batch, group). 64*64*16 = 65536 elems each.
// ---------------------------------------------------------------------------
__global__ __launch_bounds__(256) void gn_stats(const float* __restrict__ x,
                                                float* __restrict__ stats) {
    const int bg = blockIdx.x;            // 0..127
    const int b = bg >> 5, g = bg & 31;
    const float* base = x + (long)b * (4096L * 512) + g * 16;
    const int tid = threadIdx.x;
    float s = 0.f, sq = 0.f;
    #pragma unroll 8
    for (int i = 0; i < 64; i++) {
        int idx4 = tid + i * 256;          // float4 index within group
        int pixel = idx4 >> 2, c4 = idx4 & 3;
        const float4 v = *(const float4*)(base + (long)pixel * 512 + c4 * 4);
        s += v.x + v.y + v.z + v.w;
        sq += v.x * v.x + v.y * v.y + v.z * v.z + v.w * v.w;
    }
    #pragma unroll
    for (int off = 32; off > 0; off >>= 1) {
        s += __shfl_down(s, off);
        sq += __shfl_down(sq, off);
    }
    __shared__ float rs[4], rq[4];
    const int lane = tid & 63, w = tid >> 6;
    if (lane == 0) { rs[w] = s; rq[w] = sq; }
    __syncthreads();
    if (tid == 0) {
        float S = rs[0] + rs[1] + rs[2] + rs[3];
        float Q = rq[0] + rq[1] + rq[2] + rq[3];
        float mean = S * (1.f / 65536.f);
        float var = Q * (1.f / 65536.f) - mean * mean;
        stats[bg * 2 + 0] = mean;
        stats[bg * 2 + 1] = rsqrtf(var + 1e-5f);
    }
}

// ---------------------------------------------------------------------------
// GroupNorm apply: h_bf16 = (x-mean)*rstd*gamma + beta.  4 elems/thread.
// ---------------------------------------------------------------------------
__global__ __launch_bounds__(256) void gn_apply(const float* __restrict__ x,
                                                const float* __restrict__ stats,
                                                const float* __restrict__ gamma,
                                                const float* __restrict__ beta,
                                                uint16_t* __restrict__ h) {
    const long idx4 = (long)blockIdx.x * 256 + threadIdx.x;   // 0..2097151
    const long e0 = idx4 * 4;
    const int c = (int)(e0 & 511);
    const int b = (int)(e0 >> 21);                            // 4096*512 = 2^21
    const float2 st = ((const float2*)stats)[b * 32 + (c >> 4)];
    const float4 v = ((const float4*)x)[idx4];
    const float4 gm = ((const float4*)gamma)[c >> 2];
    const float4 bt = ((const float4*)beta)[c >> 2];
    union { ushort4 u; uint16_t s[4]; } o;
    o.s[0] = f2b((v.x - st.x) * st.y * gm.x + bt.x);
    o.s[1] = f2b((v.y - st.x) * st.y * gm.y + bt.y);
    o.s[2] = f2b((v.z - st.x) * st.y * gm.z + bt.z);
    o.s[3] = f2b((v.w - st.x) * st.y * gm.w + bt.w);
    ((ushort4*)h)[idx4] = o.u;
}

// ---------------------------------------------------------------------------
// Cast+transpose weights: wT[d][c] = bf16(w[c][d]), 512x512, 64x64 LDS tiles.
// grid (8, 8, 4): z selects which weight matrix.
// ---------------------------------------------------------------------------
__global__ __launch_bounds__(256) void wcast_transpose(const float* __restrict__ w0,
                                                       const float* __restrict__ w1,
                                                       const float* __restrict__ w2,
                                                       const float* __restrict__ w3,
                                                       uint16_t* __restrict__ out) {
    const float* ws[4] = {w0, w1, w2, w3};
    const float* w = ws[blockIdx.z];
    uint16_t* o = out + (long)blockIdx.z * 512 * 512;
    __shared__ uint16_t t[64][65];
    const int nb = blockIdx.x * 64, kb = blockIdx.y * 64;
    const int lc = threadIdx.x & 63, lg = threadIdx.x >> 6;
    #pragma unroll
    for (int i = 0; i < 16; i++) {
        int r = lg * 16 + i;
        t[lc][r] = f2b(w[(long)(kb + r) * 512 + nb + lc]);   // t[n_loc][k_loc]
    }
    __syncthreads();
    #pragma unroll
    for (int i = 0; i < 16; i++) {
        int r = lg * 16 + i;
        o[(long)(nb + r) * 512 + kb + lc] = t[r][lc];        // wT[n][k]
    }
}

// ---------------------------------------------------------------------------
// Transpose v (bf16): vT[b][c][n] = v[b][n][c].  64x64 tiles, grid (8, 64, 4).
// ---------------------------------------------------------------------------
__global__ __launch_bounds__(256) void transpose_v(const uint16_t* __restrict__ v,
                                                   uint16_t* __restrict__ vt) {
    __shared__ uint16_t t[64][65];
    const long zb = blockIdx.z;
    const uint16_t* in = v + zb * (4096L * 512);
    uint16_t* out = vt + zb * (512L * 4096);
    const int cb = blockIdx.x * 64;    // channel tile
    const int rb = blockIdx.y * 64;    // pixel tile
    const int lc = threadIdx.x & 63, lg = threadIdx.x >> 6;
    #pragma unroll
    for (int i = 0; i < 16; i++) {
        int r = lg * 16 + i;
        t[lc][r] = in[(long)(rb + r) * 512 + cb + lc];
    }
    __syncthreads();
    #pragma unroll
    for (int i = 0; i < 16; i++) {
        int r = lg * 16 + i;
        out[(long)(cb + r) * 4096 + rb + lc] = t[r][lc];
    }
}

// ---------------------------------------------------------------------------
// In-place row softmax on bf16 scores. One block per row (4096 cols).
// ---------------------------------------------------------------------------
__global__ __launch_bounds__(256) void softmax_inplace(uint16_t* __restrict__ s) {
    const long row = blockIdx.x;
    uint16_t* p = s + row * 4096;
    const int tid = threadIdx.x;
    union { uint4 u; uint16_t s16[8]; } d0, d1;
    d0.u = ((const uint4*)p)[tid * 2 + 0];
    d1.u = ((const uint4*)p)[tid * 2 + 1];
    float x[16];
    #pragma unroll
    for (int j = 0; j < 8; j++) { x[j] = b2f(d0.s16[j]); x[8 + j] = b2f(d1.s16[j]); }

    float m = -3.0e38f;
    #pragma unroll
    for (int j = 0; j < 16; j++) m = fmaxf(m, x[j]);
    #pragma unroll
    for (int off = 32; off > 0; off >>= 1) m = fmaxf(m, __shfl_xor(m, off));
    __shared__ float rm[4];
    const int lane = tid & 63, w = tid >> 6;
    if (lane == 0) rm[w] = m;
    __syncthreads();
    m = fmaxf(fmaxf(rm[0], rm[1]), fmaxf(rm[2], rm[3]));

    float sum = 0.f;
    #pragma unroll
    for (int j = 0; j < 16; j++) { x[j] = __expf(x[j] - m); sum += x[j]; }
    #pragma unroll
    for (int off = 32; off > 0; off >>= 1) sum += __shfl_xor(sum, off);
    __shared__ float rsum[4];
    if (lane == 0) rsum[w] = sum;
    __syncthreads();
    sum = rsum[0] + rsum[1] + rsum[2] + rsum[3];
    const float inv = 1.f / sum;

    #pragma unroll
    for (int j = 0; j < 8; j++) { d0.s16[j] = f2b(x[j] * inv); d1.s16[j] = f2b(x[8 + j] * inv); }
    ((uint4*)p)[tid * 2 + 0] = d0.u;
    ((uint4*)p)[tid * 2 + 1] = d1.u;
}

// ---------------------------------------------------------------------------
// Templated bf16 MFMA GEMM, m97 structure + XOR-swizzled LDS + repack epilogue.
// C[m,n] = sum_k A[m,k] * Bt[n,k]   (both row-major with K contiguous)
// MODE 0: bf16 out, (acc + bias[n]) * scale
// MODE 1: bf16 out, plain
// MODE 2: f32 out, acc + bias[n] + resid[m*N+n]
// Tile: 128x128, BK=64, 4 waves each computing 64x64 via 4x4 of 16x16x32 MFMA.
// LDS swizzle: chunk (row, j) of the tile holds global chunk (row, j^(row&7)).
// Achieved by permuting the GLOBAL source address (LDS dest of global_load_lds
// must remain lane-linear). Fragment reads XOR back -> 2-way banks (free).
// ---------------------------------------------------------------------------
template <int MODE>
__global__ __launch_bounds__(256) void gemm_bt(const uint16_t* __restrict__ A,
                                               const uint16_t* __restrict__ B,
                                               void* __restrict__ Cout,
                                               const float* __restrict__ bias,
                                               const float* __restrict__ resid,
                                               float scale, int M, int N, int K,
                                               long aStride, long bStride, long cStride) {
    // staging: sA=smem[0..8191], sB=smem[8192..16383] (each 128 rows x 64 bf16)
    // epilogue: reuses smem as 128 x 136 bf16 (stride 136 keeps 16B alignment,
    // spreads banks by 4/row)
    __shared__ __align__(16) uint16_t smem[128 * 136];
    uint16_t* sA = smem;
    uint16_t* sB = smem + 8192;

    const int tid = threadIdx.x;
    const int bz = blockIdx.z;
    const long m0 = (long)blockIdx.y * 128;
    const long n0 = (long)blockIdx.x * 128;
    const uint16_t* Ab = A + (long)bz * aStride;
    const uint16_t* Bb = B + (long)bz * bStride;

    const int lane = tid & 63;
    const int wave = tid >> 6;
    const int wm = (wave & 1) * 64;
    const int wn = (wave >> 1) * 64;
    const int fr = lane & 15;          // fragment row (m for A, n for B)
    const int fh = lane >> 4;          // k-chunk selector (fk = fh*8)
    const int sw = fr & 7;             // swizzle key (row&7 == fr&7 here)

    floatx4 acc[4][4];
    #pragma unroll
    for (int i = 0; i < 4; i++)
        #pragma unroll
        for (int j = 0; j < 4; j++) acc[i][j] = (floatx4){0.f, 0.f, 0.f, 0.f};

    for (int kt = 0; kt < K; kt += 64) {
        __syncthreads();   // previous compute done before overwriting LDS
        #pragma unroll
        for (int i = 0; i < 4; i++) {
            const int c = i * 256 + tid;        // chunk id: lane-linear per wave
            const int row = c >> 3;
            const int gj = (c & 7) ^ (row & 7); // source k-chunk (swizzled)
            lds_copy16(&sA[c * 8], Ab + (m0 + row) * (long)K + kt + gj * 8);
            lds_copy16(&sB[c * 8], Bb + (n0 + row) * (long)K + kt + gj * 8);
        }
        __syncthreads();   // drains vmcnt before barrier (compiler-enforced)
        #pragma unroll
        for (int kk = 0; kk < 64; kk += 32) {
            const int jx = ((fh + (kk >> 3)) ^ sw) * 8;  // swizzled chunk offset
            bf16x8 av[4], bv[4];
            #pragma unroll
            for (int mi = 0; mi < 4; mi++)
                av[mi] = *(const bf16x8*)&sA[(wm + mi * 16 + fr) * 64 + jx];
            #pragma unroll
            for (int ni = 0; ni < 4; ni++)
                bv[ni] = *(const bf16x8*)&sB[(wn + ni * 16 + fr) * 64 + jx];
            #pragma unroll
            for (int mi = 0; mi < 4; mi++)
                #pragma unroll
                for (int ni = 0; ni < 4; ni++)
                    acc[mi][ni] = __builtin_amdgcn_mfma_f32_16x16x32_bf16(
                        av[mi], bv[ni], acc[mi][ni], 0, 0, 0);
        }
    }

    // Epilogue.  C/D layout (verified m89/m91): col = lane&15, row = quad*4+reg
    const int quad = lane >> 4;
    if (MODE == 2) {
        #pragma unroll
        for (int ni = 0; ni < 4; ni++) {
            const long col = n0 + wn + ni * 16 + fr;
            const float bv_ = bias[col];
            #pragma unroll
            for (int mi = 0; mi < 4; mi++) {
                #pragma unroll
                for (int r = 0; r < 4; r++) {
                    const long row = m0 + wm + mi * 16 + quad * 4 + r;
                    float v = acc[mi][ni][r] + bv_ + resid[row * (long)N + col];
                    ((float*)Cout)[row * (long)N + col] = v;
                }
            }
        }
    } else {
        __syncthreads();   // done with sA/sB; reuse as 128x136 repack buffer
        #pragma unroll
        for (int ni = 0; ni < 4; ni++) {
            const int col_l = wn + ni * 16 + fr;
            const float bv_ = (MODE == 0) ? bias[n0 + col_l] : 0.f;
            #pragma unroll
            for (int mi = 0; mi < 4; mi++) {
                #pragma unroll
                for (int r = 0; r < 4; r++) {
                    const int row_l = wm + mi * 16 + quad * 4 + r;
                    float v = acc[mi][ni][r];
                    if (MODE == 0) v = (v + bv_) * scale;
                    smem[row_l * 136 + col_l] = f2b(v);
                }
            }
        }
        __syncthreads();
        uint16_t* Cb = (uint16_t*)Cout + (long)bz * cStride;
        #pragma unroll
        for (int it = 0; it < 8; it++) {
            const int row_l = it * 16 + (tid >> 4);
            const int c0 = (tid & 15) * 8;
            const uint4 d = *(const uint4*)&smem[row_l * 136 + c0];
            *(uint4*)&Cb[(m0 + row_l) * (long)N + n0 + c0] = d;
        }
    }
}

// ---------------------------------------------------------------------------
extern "C" void kernel_launch(void* const* d_in, const int* in_sizes, int n_in,
                              void* d_out, int out_size, void* d_ws, size_t ws_size,
                              hipStream_t stream) {
    const float* x  = (const float*)d_in[0];
    const float* gg = (const float*)d_in[1];
    const float* gb = (const float*)d_in[2];
    const float* wq = (const float*)d_in[3];
    const float* bq = (const float*)d_in[4];
    const float* wk = (const float*)d_in[5];
    const float* bk = (const float*)d_in[6];
    const float* wv = (const float*)d_in[7];
    const float* bv = (const float*)d_in[8];
    const float* wp = (const float*)d_in[9];
    const float* bp = (const float*)d_in[10];
    float* out = (float*)d_out;

    char* ws = (char*)d_ws;
    size_t off = 0;
    auto alloc = [&](size_t bytes) {
        char* p = ws + off;
        off += (bytes + 255) & ~(size_t)255;
        return p;
    };
    float*    stats = (float*)alloc(128 * 2 * sizeof(float));
    uint16_t* h     = (uint16_t*)alloc(16384L * 512 * 2);
    uint16_t* wT    = (uint16_t*)alloc(4L * 512 * 512 * 2);
    uint16_t* q     = (uint16_t*)alloc(16384L * 512 * 2);
    uint16_t* k     = (uint16_t*)alloc(16384L * 512 * 2);
    uint16_t* v     = (uint16_t*)alloc(16384L * 512 * 2);
    uint16_t* vt    = (uint16_t*)alloc(16384L * 512 * 2);
    uint16_t* sc    = (uint16_t*)alloc(4L * 4096 * 4096 * 2);
    uint16_t* ao    = (uint16_t*)alloc(16384L * 512 * 2);
    if (off > ws_size) return;  // workspace too small -> fail visibly

    gn_stats<<<128, 256, 0, stream>>>(x, stats);
    gn_apply<<<8192, 256, 0, stream>>>(x, stats, gg, gb, h);
    wcast_transpose<<<dim3(8, 8, 4), 256, 0, stream>>>(wq, wk, wv, wp, wT);

    const float qscale = 0.04419417382415922f;  // 512^-0.5
    // QKV projections: [16384,512] x [512,512]
    gemm_bt<0><<<dim3(4, 128, 1), 256, 0, stream>>>(h, wT,              q, bq, nullptr, qscale,
                                                    16384, 512, 512, 0, 0, 0);
    gemm_bt<0><<<dim3(4, 128, 1), 256, 0, stream>>>(h, wT + 262144,     k, bk, nullptr, 1.f,
                                                    16384, 512, 512, 0, 0, 0);
    gemm_bt<0><<<dim3(4, 128, 1), 256, 0, stream>>>(h, wT + 2 * 262144, v, bv, nullptr, 1.f,
                                                    16384, 512, 512, 0, 0, 0);
    // scores[b] = q[b] @ k[b]^T  (scale already folded into q)
    gemm_bt<1><<<dim3(32, 32, 4), 256, 0, stream>>>(q, k, sc, nullptr, nullptr, 1.f,
                                                    4096, 4096, 512,
                                                    4096L * 512, 4096L * 512, 4096L * 4096);
    softmax_inplace<<<16384, 256, 0, stream>>>(sc);
    transpose_v<<<dim3(8, 64, 4), 256, 0, stream>>>(v, vt);
    // attn_out[b] = attn[b] @ v[b]
    gemm_bt<1><<<dim3(4, 32, 4), 256, 0, stream>>>(sc, vt, ao, nullptr, nullptr, 1.f,
                                                   4096, 512, 4096,
                                                   4096L * 4096, 512L * 4096, 4096L * 512);
    // out = x + attn_out @ wp + bp
    gemm_bt<2><<<dim3(4, 128, 1), 256, 0, stream>>>(ao, wT + 3 * 262144, out, bp, x, 1.f,
                                                    16384, 512, 512, 0, 0, 0);
}